// Round 1
// baseline (82.865 us; speedup 1.0000x reference)
//
#include <hip/hip_runtime.h>

// SoftRank: out[b,j,c] = (1/N) * sum_i sigmoid(ALPHA*(x[b,j,c]-x[b,i,c]))
// B=8, N=1024, C=16, fp32. Trans-bound: 1 v_exp + 1 v_rcp per term.
// sigmoid(z) = 1/(1+exp(-z)); with z = ALPHA*(xj-xi):
//   exp(-z) = exp2(K*xi - K*xj), K = ALPHA*log2(e).
// Premultiply K into the LDS-staged values so inner loop is sub/exp2/add/rcp/add.

#define K_LOG2E 1442.6950408889634f  // 1000 * log2(e)

constexpr int Bdim = 8;
constexpr int Ndim = 1024;
constexpr int Cdim = 16;
constexpr int ITILE = 512;     // i-tile in LDS: 512*16*4B = 32 KB
constexpr int THREADS = 256;   // 16 j x 16 c per block

__global__ __launch_bounds__(THREADS)
void softrank_kernel(const float* __restrict__ x, float* __restrict__ out) {
    __shared__ float xs[ITILE * Cdim];

    const int tid = threadIdx.x;
    const int c  = tid & 15;    // channel
    const int jl = tid >> 4;    // 0..15 local j
    const int blk = blockIdx.x; // 0..511
    const int b      = blk >> 6;   // blk / 64
    const int jchunk = blk & 63;   // 64 chunks of 16 j
    const int j = jchunk * 16 + jl;

    const float* xb = x + b * (Ndim * Cdim);
    const float vj = K_LOG2E * xb[j * Cdim + c];

    float acc = 0.0f;

    for (int it = 0; it < Ndim; it += ITILE) {
        // Cooperative tile load: ITILE*Cdim floats = 2048 float4, 8 per thread.
        // Contiguous global -> contiguous LDS, premultiplied by K.
        const float4* __restrict__ src = (const float4*)(xb + it * Cdim);
        float4* dst = (float4*)xs;
        #pragma unroll
        for (int k = 0; k < (ITILE * Cdim / 4) / THREADS; ++k) {
            float4 v = src[tid + k * THREADS];
            v.x *= K_LOG2E; v.y *= K_LOG2E; v.z *= K_LOG2E; v.w *= K_LOG2E;
            dst[tid + k * THREADS] = v;
        }
        __syncthreads();

        // Inner loop: 16 unique LDS addresses/wave (broadcast over 4 j-lanes),
        // banks (16*i+c)%32 -> 16 distinct banks, conflict-free.
        #pragma unroll 8
        for (int i = 0; i < ITILE; ++i) {
            float t = xs[i * Cdim + c] - vj;             // v_sub
            float e = __builtin_amdgcn_exp2f(t);         // v_exp_f32
            acc += __builtin_amdgcn_rcpf(1.0f + e);      // v_add, v_rcp, v_add
        }
        __syncthreads();
    }

    // Coalesced store: consecutive tid -> consecutive (j,c) -> contiguous floats.
    out[b * (Ndim * Cdim) + j * Cdim + c] = acc * (1.0f / (float)Ndim);
}

extern "C" void kernel_launch(void* const* d_in, const int* in_sizes, int n_in,
                              void* d_out, int out_size, void* d_ws, size_t ws_size,
                              hipStream_t stream) {
    (void)in_sizes; (void)n_in; (void)d_ws; (void)ws_size; (void)out_size;
    const float* x = (const float*)d_in[0];
    float* out = (float*)d_out;
    const int grid = Bdim * (Ndim / 16);  // 512 blocks
    softrank_kernel<<<grid, THREADS, 0, stream>>>(x, out);
}

// Round 2
// 56.926 us; speedup vs baseline: 1.4557x; 1.4557x over previous
//
#include <hip/hip_runtime.h>

// SoftRank via per-column counting-sort + windowed exact sigmoid.
// out[b,j,c] = (1/N) * sum_i sigmoid(1000*(x[b,j,c]-x[b,i,c]))
// With ALPHA=1000, terms saturate outside |dx| ~ 0.012. Per (b,c) column:
//   1) bucket-sort the 1024 values (1024 buckets over [-6,6))
//   2) out[j] = ( #{i in buckets <= k-2} + sum_{i in buckets k-1..k+1} sigmoid )/N
// Bucket width in log2-units = 12*K/NB = 16.9 -> omitted-term error 2^-16.9 each.
// Trans count: 134M -> ~1.7M.

#define K_LOG2E 1442.6950408889634f  // 1000 * log2(e)

constexpr int Bdim = 8;
constexpr int Ndim = 1024;
constexpr int Cdim = 16;
constexpr int NB   = 1024;          // buckets (== blockDim for easy init/scan)
constexpr float RANGE = 6.0f;       // bucket domain [-6, 6) in raw units

__global__ __launch_bounds__(1024)
void softrank_bucket(const float* __restrict__ x, float* __restrict__ out) {
    __shared__ int   cnt[NB];   // histogram
    __shared__ int   cum[NB];   // inclusive prefix after scan
    __shared__ int   off[NB];   // scatter cursors
    __shared__ float sv[Ndim];  // bucket-ordered scaled values

    const int t = threadIdx.x;          // element index i in the column
    const int b = blockIdx.x >> 4;
    const int c = blockIdx.x & 15;

    // Load my element (scaled to log2-sigmoid units).
    const float v = K_LOG2E * x[b * (Ndim * Cdim) + t * Cdim + c];

    // Bucket index.
    const float inv_w = (float)NB / (2.0f * RANGE * K_LOG2E);
    int k = (int)floorf((v + RANGE * K_LOG2E) * inv_w);
    k = min(max(k, 0), NB - 1);

    // Histogram.
    cnt[t] = 0;
    __syncthreads();
    atomicAdd(&cnt[k], 1);
    __syncthreads();

    // Inclusive prefix sum over buckets (Hillis-Steele, 10 steps).
    const int myc = cnt[t];
    cum[t] = myc;
    __syncthreads();
    for (int d = 1; d < NB; d <<= 1) {
        int add = (t >= d) ? cum[t - d] : 0;
        __syncthreads();
        cum[t] += add;
        __syncthreads();
    }

    // Scatter into bucket order.
    off[t] = cum[t] - myc;   // exclusive prefix = cursor start
    __syncthreads();
    int pos = atomicAdd(&off[k], 1);
    sv[pos] = v;
    __syncthreads();

    // Window = buckets [k-1, k+1]; everything in buckets <= k-2 contributes ~1
    // (scaled distance > 16.9 log2-units, deficit 2^-16.9 per term).
    const int lo = (k >= 2) ? cum[k - 2] : 0;            // excl prefix of bucket k-1
    const int hi = (k + 1 <= NB - 1) ? cum[k + 1] : Ndim; // incl prefix of bucket k+1

    float acc = 0.0f;
    for (int p = lo; p < hi; ++p) {
        float u = v - sv[p];                         // log2-units; |u| <= 33.8
        float e = __builtin_amdgcn_exp2f(-u);        // exp(-alpha*dx)
        acc += __builtin_amdgcn_rcpf(1.0f + e);      // sigmoid
    }

    out[b * (Ndim * Cdim) + t * Cdim + c] = ((float)lo + acc) * (1.0f / (float)Ndim);
}

extern "C" void kernel_launch(void* const* d_in, const int* in_sizes, int n_in,
                              void* d_out, int out_size, void* d_ws, size_t ws_size,
                              hipStream_t stream) {
    (void)in_sizes; (void)n_in; (void)d_ws; (void)ws_size; (void)out_size;
    const float* x = (const float*)d_in[0];
    float* out = (float*)d_out;
    softrank_bucket<<<Bdim * Cdim, 1024, 0, stream>>>(x, out);
}